// Round 11
// baseline (319.406 us; speedup 1.0000x reference)
//
#include <hip/hip_runtime.h>
#include <hip/hip_bf16.h>
#include <stdint.h>

typedef __bf16 bf16x8 __attribute__((ext_vector_type(8)));
typedef float  f32x4  __attribute__((ext_vector_type(4)));
typedef unsigned short u16;
typedef unsigned int   u32;
typedef u16 u16x4 __attribute__((ext_vector_type(4)));
typedef u32 u32x4 __attribute__((ext_vector_type(4)));

#define B_  32
#define N_  128
#define F_  128
#define G_  300
#define GP  320
#define TAB_N 4096
#define TAB_SCALE 128.0f   // 1/delta ; nearest-neighbor table, d in [0, 32)

__device__ __forceinline__ u16 f2b(float f){
  union { float f; u32 u; } x; x.f = f;
  u32 r = x.u + 0x7FFFu + ((x.u >> 16) & 1u);
  return (u16)(r >> 16);
}
__device__ __forceinline__ u32 pack2bf(float a, float b){
  return __builtin_amdgcn_perm(__float_as_uint(b) + 0x8000u,
                               __float_as_uint(a) + 0x8000u, 0x07060302u);
}
__device__ __forceinline__ float sspf(float x){
  return fmaxf(x, 0.0f) + __logf(0.5f + 0.5f*__expf(-fabsf(x)));
}
__device__ __forceinline__ f32x4 mfma16(bf16x8 a, bf16x8 b, f32x4 c){
  return __builtin_amdgcn_mfma_f32_16x16x32_bf16(a, b, c, 0, 0, 0);
}

// ---------------- setup: transpose+cast all weights to bf16 [h][k] ---------
__global__ __launch_bounds__(256) void k_setup(const float* __restrict__ w_f1,
                                               const float* __restrict__ w_f2,
                                               const float* __restrict__ w_in2f,
                                               const float* __restrict__ w_f2out,
                                               const float* __restrict__ w_out,
                                               const float* __restrict__ w_aw1,
                                               u16* __restrict__ w1t,
                                               u16* __restrict__ w2t,
                                               u16* __restrict__ wi2t,
                                               u16* __restrict__ w2outT,
                                               u16* __restrict__ woutT,
                                               u16* __restrict__ waw1T){
  int idx = blockIdx.x*256 + threadIdx.x;      // < 40960 + 5*16384 = 122880
  if (idx < 128*GP){
    int h = idx / GP, g = idx % GP;
    w1t[idx] = (g < G_) ? f2b(w_f1[g*F_ + h]) : (u16)0;
  } else {
    int j = idx - 128*GP;
    int which = j >> 14;
    int rr = j & 16383;
    int h = rr >> 7, k = rr & 127;
    const float* src; u16* dst;
    switch (which){
      case 0:  src = w_f2;    dst = w2t;    break;
      case 1:  src = w_in2f;  dst = wi2t;   break;
      case 2:  src = w_f2out; dst = w2outT; break;
      case 3:  src = w_out;   dst = woutT;  break;
      default: src = w_aw1;   dst = waw1T;  break;
    }
    dst[h*128 + k] = f2b(src[k*128 + h]);
  }
}

// ---- prep: gentab (blk 0-255) | lin (256-383) | pairidx NN (384-447) ----
__global__ __launch_bounds__(256) void k_prep(const u16* __restrict__ w1t,
                                              const u16* __restrict__ w2t,
                                              const float* __restrict__ b_f1,
                                              const float* __restrict__ b_f2,
                                              u16* __restrict__ tab,
                                              const int* __restrict__ z,
                                              const float* __restrict__ emb,
                                              const u16* __restrict__ wi2t,
                                              u16* __restrict__ fb,
                                              const float* __restrict__ r,
                                              u16* __restrict__ dIdx){
  __shared__ __attribute__((aligned(16))) u16 w1s[16][136];
  __shared__ float rshp[128][3];
  int blk = blockIdx.x;
  int tid = threadIdx.x, lane = tid & 63, wave = tid >> 6;
  int m = lane & 15, q = lane >> 4;

  if (blk < 256){
    // ---- table tile: h(d) for d=(t0+row)/128, MFMA over K1=320, K2=128 ----
    int t0 = blk * 16;
    int C0 = wave*32;
    const float K2 = 14.4269504089f;           // gamma * log2(e)
    const float DC = 30.0f/299.0f;
    float d = (float)(t0 + m) * (1.0f/TAB_SCALE);
    f32x4 acc[2];
    acc[0] = (f32x4){0.f,0.f,0.f,0.f}; acc[1] = (f32x4){0.f,0.f,0.f,0.f};
    #pragma unroll
    for (int ks = 0; ks < 10; ++ks){
      int kb = ks*32 + q*8;
      u32x4 au;
      #pragma unroll
      for (int t2 = 0; t2 < 4; ++t2){
        int k0 = kb + t2*2;
        float u0 = d - DC*(float)k0;
        float u1 = d - DC*(float)(k0 + 1);
        float e0 = __builtin_amdgcn_exp2f(-K2*u0*u0);
        float e1 = __builtin_amdgcn_exp2f(-K2*u1*u1);
        au[t2] = pack2bf(e0, e1);
      }
      bf16x8 af = __builtin_bit_cast(bf16x8, au);
      #pragma unroll
      for (int ni = 0; ni < 2; ++ni){
        bf16x8 bfv = *reinterpret_cast<const bf16x8*>(w1t + (size_t)(C0 + ni*16 + m)*GP + kb);
        acc[ni] = mfma16(af, bfv, acc[ni]);
      }
    }
    #pragma unroll
    for (int ni = 0; ni < 2; ++ni)
      #pragma unroll
      for (int rr = 0; rr < 4; ++rr){
        int col = C0 + ni*16 + m;
        w1s[q*4 + rr][col & 127] = f2b(sspf(acc[ni][rr] + b_f1[col]));
      }
    __syncthreads();
    f32x4 acc2[2];
    acc2[0] = (f32x4){0.f,0.f,0.f,0.f}; acc2[1] = (f32x4){0.f,0.f,0.f,0.f};
    #pragma unroll
    for (int ks = 0; ks < 4; ++ks){
      int kb = ks*32 + q*8;
      bf16x8 af = *reinterpret_cast<const bf16x8*>(&w1s[m][kb]);
      #pragma unroll
      for (int ni = 0; ni < 2; ++ni){
        bf16x8 bfv = *reinterpret_cast<const bf16x8*>(w2t + (size_t)(C0 + ni*16 + m)*128 + kb);
        acc2[ni] = mfma16(af, bfv, acc2[ni]);
      }
    }
    #pragma unroll
    for (int ni = 0; ni < 2; ++ni)
      #pragma unroll
      for (int rr = 0; rr < 4; ++rr){
        int col = C0 + ni*16 + m;
        tab[(size_t)(t0 + q*4 + rr)*F_ + col] = f2b(acc2[ni][rr] + b_f2[col]);
      }
  } else if (blk < 384){
    // ---- f = emb[z] @ w_in2f (first iteration's cfconv input) ----
    int bi = blk - 256;
    int b = bi >> 2, qd = bi & 3;
    int R0 = qd*32 + (wave >> 1)*16;
    int C0 = (wave & 1)*64;
    int row = R0 + m;
    const float* erow = emb + (size_t)z[b*N_ + row]*F_;
    f32x4 acc[4];
    #pragma unroll
    for (int ni = 0; ni < 4; ++ni) acc[ni] = (f32x4){0.f,0.f,0.f,0.f};
    #pragma unroll
    for (int ks = 0; ks < 4; ++ks){
      int k0 = ks*32 + q*8;
      float4 e0 = *reinterpret_cast<const float4*>(erow + k0);
      float4 e1 = *reinterpret_cast<const float4*>(erow + k0 + 4);
      u32x4 au;
      au[0] = pack2bf(e0.x, e0.y); au[1] = pack2bf(e0.z, e0.w);
      au[2] = pack2bf(e1.x, e1.y); au[3] = pack2bf(e1.z, e1.w);
      bf16x8 af = __builtin_bit_cast(bf16x8, au);
      #pragma unroll
      for (int ni = 0; ni < 4; ++ni){
        bf16x8 bfv = *reinterpret_cast<const bf16x8*>(wi2t + (size_t)(C0 + ni*16 + m)*F_ + k0);
        acc[ni] = mfma16(af, bfv, acc[ni]);
      }
    }
    u16* fbb = fb + (size_t)b*N_*F_;
    #pragma unroll
    for (int ni = 0; ni < 4; ++ni)
      #pragma unroll
      for (int rr = 0; rr < 4; ++rr)
        fbb[(size_t)(R0 + q*4 + rr)*F_ + C0 + ni*16 + m] = f2b(acc[ni][rr]);
  } else {
    // ---- pair index (NN): ix = round(|r_i - r_j| * 128), clamp 4095 ----
    int pb = blk - 384;                  // 64 blocks: (b, i-half)
    int b = pb >> 1, i0p = (pb & 1)*64;
    if (tid < 128){
      const float* rp = r + (size_t)(b*N_ + tid)*3;
      rshp[tid][0] = rp[0]; rshp[tid][1] = rp[1]; rshp[tid][2] = rp[2];
    }
    __syncthreads();
    #pragma unroll
    for (int t = 0; t < 32; ++t){
      int p = t*256 + tid;               // (il<64, j<128)
      int il = p >> 7, j = p & 127;
      int i = i0p + il;
      float dx = rshp[i][0] - rshp[j][0];
      float dy = rshp[i][1] - rshp[j][1];
      float dz = rshp[i][2] - rshp[j][2];
      float d = sqrtf(fmaf(dx,dx, fmaf(dy,dy, fmaf(dz,dz, 1e-12f))));
      int ix = (int)(d * TAB_SCALE + 0.5f);
      if (ix > TAB_N - 1) ix = TAB_N - 1;
      dIdx[((size_t)(b*N_ + i))*N_ + j] = (u16)ix;
    }
  }
}

// ---------------- cfconv (NN): y[i,h] = sum_j tab[ix_ij][h] * f[j,h] -------
// grid 2048 = (b, 64 i-tiles of 2). 8 blocks/CU. Thread = (jq8, il2, chg16).
// Pair indices preloaded into REGISTERS from global (32B/thread, L2-hot):
// removes the per-iteration LDS->VMEM dependency + the staging barrier.
__global__ __launch_bounds__(256, 8) void k_conv(const u16* __restrict__ fb,
                                                 const u16* __restrict__ tab,
                                                 const u16* __restrict__ dIdx,
                                                 u16* __restrict__ yb){
  __shared__ __attribute__((aligned(16))) float psh[8][2][128];
  int bid = blockIdx.x;
  int b = bid >> 6, i0 = (bid & 63)*2;
  int tid = threadIdx.x;
  int chg = tid & 15, il = (tid >> 4) & 1, jq = tid >> 5;
  int h0 = chg*8;

  // preload this thread's 16 pair indices (32 contiguous bytes)
  const u16* dp = dIdx + ((size_t)(b*N_ + i0 + il))*N_ + jq*16;
  u32x4 iA = *reinterpret_cast<const u32x4*>(dp);
  u32x4 iB = *reinterpret_cast<const u32x4*>(dp + 8);
  u32 idx[16];
  #pragma unroll
  for (int t = 0; t < 4; ++t){
    idx[t*2]     = iA[t] & 0xFFFFu;  idx[t*2 + 1] = iA[t] >> 16;
    idx[8 + t*2] = iB[t] & 0xFFFFu;  idx[8 + t*2 + 1] = iB[t] >> 16;
  }

  const u16* tb0 = tab + h0;
  const u16* fbp = fb + (size_t)b*N_*F_ + (size_t)(jq*16)*F_ + h0;
  float yv[8] = {0,0,0,0,0,0,0,0};
  #pragma unroll
  for (int jj = 0; jj < 16; ++jj){
    bf16x8 ta = *reinterpret_cast<const bf16x8*>(tb0 + ((size_t)idx[jj] << 7));
    bf16x8 fv = *reinterpret_cast<const bf16x8*>(fbp + (size_t)jj*F_);
    #pragma unroll
    for (int t = 0; t < 8; ++t)
      yv[t] = fmaf((float)ta[t], (float)fv[t], yv[t]);
  }
  {
    float* pp = &psh[jq][il][h0];
    *reinterpret_cast<float4*>(pp)     = (float4){yv[0], yv[1], yv[2], yv[3]};
    *reinterpret_cast<float4*>(pp + 4) = (float4){yv[4], yv[5], yv[6], yv[7]};
  }
  __syncthreads();
  int ilo = tid >> 7, cho = tid & 127;
  float s = 0.f;
  #pragma unroll
  for (int t = 0; t < 8; ++t) s += psh[t][ilo][cho];
  yb[((size_t)(b*N_ + i0 + ilo))*F_ + cho] = f2b(s);
}

// ---------------- MLP chain via MFMA (+readout on last) ----------------
// grid 256 (b, 16-row tile) x 512 threads: 8 waves, each owns a 16-col slice.
// (round-8 measured-best form: single MFMA chain per GEMM)
__global__ __launch_bounds__(512) void k_mlp(const u16* __restrict__ yb,
                                             float* __restrict__ x,
                                             const int* __restrict__ z,
                                             const float* __restrict__ emb,
                                             const u16* __restrict__ w2outT,
                                             const float* __restrict__ b_f2out,
                                             const u16* __restrict__ woutT,
                                             const float* __restrict__ b_out,
                                             const u16* __restrict__ wi2t,
                                             const u16* __restrict__ waw1T,
                                             const float* __restrict__ b_aw1,
                                             const float* __restrict__ w_aw2,
                                             const float* __restrict__ b_aw2,
                                             u16* __restrict__ fb,
                                             float* __restrict__ outp,
                                             int first, int mode){
  __shared__ __attribute__((aligned(16))) u16 ab[16][136];
  __shared__ float cs[16][132];
  __shared__ float psum[16][8];
  __shared__ int zsh[16];
  int tid = threadIdx.x, lane = tid & 63, wave = tid >> 6;
  int m = lane & 15, q = lane >> 4;
  int bid = blockIdx.x;
  int b = bid >> 3, R0 = (bid & 7)*16;
  int C0 = wave*16;                      // 8 waves x 16 cols
  int col = C0 + m;

  if (first && tid < 16) zsh[tid] = z[b*N_ + R0 + tid];
  { // stage y (already bf16): 512 thr x 4 ch
    int row = tid >> 5, c4 = (tid & 31)*4;
    *reinterpret_cast<u16x4*>(&ab[row][c4]) =
      *reinterpret_cast<const u16x4*>(yb + ((size_t)(b*N_ + R0 + row))*F_ + c4);
  }
  __syncthreads();

  // GEMM1: y @ w_f2out
  f32x4 acc = (f32x4){0.f,0.f,0.f,0.f};
  #pragma unroll
  for (int ks = 0; ks < 4; ++ks){
    int kb = ks*32 + q*8;
    bf16x8 af = *reinterpret_cast<const bf16x8*>(&ab[m][kb]);
    bf16x8 bfv = *reinterpret_cast<const bf16x8*>(w2outT + (size_t)col*F_ + kb);
    acc = mfma16(af, bfv, acc);
  }
  __syncthreads();
  #pragma unroll
  for (int rr = 0; rr < 4; ++rr)
    ab[q*4 + rr][col] = f2b(sspf(acc[rr] + b_f2out[col]));
  __syncthreads();

  // GEMM2: y2 @ w_out
  f32x4 acc2 = (f32x4){0.f,0.f,0.f,0.f};
  #pragma unroll
  for (int ks = 0; ks < 4; ++ks){
    int kb = ks*32 + q*8;
    bf16x8 af = *reinterpret_cast<const bf16x8*>(&ab[m][kb]);
    bf16x8 bfv = *reinterpret_cast<const bf16x8*>(woutT + (size_t)col*F_ + kb);
    acc2 = mfma16(af, bfv, acc2);
  }
  __syncthreads();
  // epilogue: x_new = x_old + v + b_out (in-place x: own rows only)
  #pragma unroll
  for (int rr = 0; rr < 4; ++rr){
    int row = q*4 + rr;
    size_t xo = (size_t)(b*N_ + R0 + row)*F_ + col;
    float xi = first ? emb[(size_t)zsh[row]*F_ + col] : x[xo];
    float nv = xi + acc2[rr] + b_out[col];
    if (mode == 0) x[xo] = nv;
    ab[row][col] = f2b(nv);
  }
  __syncthreads();

  // GEMM3: x_new @ (wi2t | waw1T)
  const u16* w3 = (mode == 0) ? wi2t : waw1T;
  f32x4 acc3 = (f32x4){0.f,0.f,0.f,0.f};
  #pragma unroll
  for (int ks = 0; ks < 4; ++ks){
    int kb = ks*32 + q*8;
    bf16x8 af = *reinterpret_cast<const bf16x8*>(&ab[m][kb]);
    bf16x8 bfv = *reinterpret_cast<const bf16x8*>(w3 + (size_t)col*F_ + kb);
    acc3 = mfma16(af, bfv, acc3);
  }
  if (mode == 0){
    #pragma unroll
    for (int rr = 0; rr < 4; ++rr)
      fb[(size_t)(b*N_ + R0 + q*4 + rr)*F_ + col] = f2b(acc3[rr]);
  } else {
    #pragma unroll
    for (int rr = 0; rr < 4; ++rr)
      cs[q*4 + rr][col] = sspf(acc3[rr] + b_aw1[col]) * w_aw2[col];
    __syncthreads();
    if (tid < 128){
      int row = tid >> 3, seg = tid & 7;
      float s = 0.f;
      #pragma unroll
      for (int t = 0; t < 16; ++t) s += cs[row][seg*16 + t];
      psum[row][seg] = s;
    }
    __syncthreads();
    if (tid < 16){
      float s = 0.f;
      #pragma unroll
      for (int t = 0; t < 8; ++t) s += psum[tid][t];
      outp[b*N_ + R0 + tid] = s + b_aw2[0];
    }
  }
}

extern "C" void kernel_launch(void* const* d_in, const int* in_sizes, int n_in,
                              void* d_out, int out_size, void* d_ws, size_t ws_size,
                              hipStream_t stream){
  const int*   z       = (const int*)d_in[0];
  const float* r       = (const float*)d_in[1];
  const float* emb     = (const float*)d_in[2];
  const float* w_in2f  = (const float*)d_in[3];
  const float* w_f1    = (const float*)d_in[4];
  const float* b_f1    = (const float*)d_in[5];
  const float* w_f2    = (const float*)d_in[6];
  const float* b_f2    = (const float*)d_in[7];
  const float* w_f2out = (const float*)d_in[8];
  const float* b_f2out = (const float*)d_in[9];
  const float* w_out   = (const float*)d_in[10];
  const float* b_out   = (const float*)d_in[11];
  const float* w_aw1   = (const float*)d_in[12];
  const float* b_aw1   = (const float*)d_in[13];
  const float* w_aw2   = (const float*)d_in[14];
  const float* b_aw2   = (const float*)d_in[15];

  // workspace layout (~6.3 MB)
  char* ws = (char*)d_ws;
  float* x     = (float*)(ws);                       // 2,097,152
  u16*   yb    = (u16*)(ws + 2097152);               // 1,048,576
  u16*   fbuf  = (u16*)(ws + 3145728);               // 1,048,576
  u16*   tab   = (u16*)(ws + 4194304);               // 1,048,576 (4096 x 128 bf16)
  u16*   dIdx  = (u16*)(ws + 5242880);               // 1,048,576
  u16*   w1t   = (u16*)(ws + 6291456);               //    81,920
  u16*   w2t   = (u16*)(ws + 6373376);               //    32,768
  u16*   wi2t  = (u16*)(ws + 6406144);               //    32,768
  u16*   w2oT  = (u16*)(ws + 6438912);               //    32,768
  u16*   woT   = (u16*)(ws + 6471680);               //    32,768
  u16*   waw1T = (u16*)(ws + 6504448);               //    32,768

  k_setup<<<480, 256, 0, stream>>>(w_f1, w_f2, w_in2f, w_f2out, w_out, w_aw1,
                                   w1t, w2t, wi2t, w2oT, woT, waw1T);
  k_prep<<<448, 256, 0, stream>>>(w1t, w2t, b_f1, b_f2, tab,
                                  z, emb, wi2t, fbuf, r, dIdx);
  // iter 1
  k_conv<<<2048, 256, 0, stream>>>(fbuf, tab, dIdx, yb);
  k_mlp<<<256, 512, 0, stream>>>(yb, x, z, emb, w2oT, b_f2out, woT, b_out,
                                 wi2t, waw1T, b_aw1, w_aw2, b_aw2,
                                 fbuf, (float*)d_out, 1, 0);
  // iter 2
  k_conv<<<2048, 256, 0, stream>>>(fbuf, tab, dIdx, yb);
  k_mlp<<<256, 512, 0, stream>>>(yb, x, z, emb, w2oT, b_f2out, woT, b_out,
                                 wi2t, waw1T, b_aw1, w_aw2, b_aw2,
                                 fbuf, (float*)d_out, 0, 0);
  // iter 3 (readout fused)
  k_conv<<<2048, 256, 0, stream>>>(fbuf, tab, dIdx, yb);
  k_mlp<<<256, 512, 0, stream>>>(yb, x, z, emb, w2oT, b_f2out, woT, b_out,
                                 wi2t, waw1T, b_aw1, w_aw2, b_aw2,
                                 fbuf, (float*)d_out, 0, 1);
}

// Round 12
// 146.260 us; speedup vs baseline: 2.1838x; 2.1838x over previous
//
#include <hip/hip_runtime.h>
#include <hip/hip_bf16.h>
#include <stdint.h>

typedef __bf16 bf16x8 __attribute__((ext_vector_type(8)));
typedef float  f32x4  __attribute__((ext_vector_type(4)));
typedef unsigned short u16;
typedef unsigned int   u32;
typedef u16 u16x4 __attribute__((ext_vector_type(4)));
typedef u32 u32x4 __attribute__((ext_vector_type(4)));

#define B_  32
#define N_  128
#define F_  128
#define G_  300
#define GP  320
#define TAB_N 4096
#define TAB_SCALE 128.0f   // 1/delta ; nearest-neighbor table, d in [0, 32)

__device__ __forceinline__ u16 f2b(float f){
  union { float f; u32 u; } x; x.f = f;
  u32 r = x.u + 0x7FFFu + ((x.u >> 16) & 1u);
  return (u16)(r >> 16);
}
__device__ __forceinline__ u32 pack2bf(float a, float b){
  return __builtin_amdgcn_perm(__float_as_uint(b) + 0x8000u,
                               __float_as_uint(a) + 0x8000u, 0x07060302u);
}
__device__ __forceinline__ float sspf(float x){
  return fmaxf(x, 0.0f) + __logf(0.5f + 0.5f*__expf(-fabsf(x)));
}
__device__ __forceinline__ f32x4 mfma16(bf16x8 a, bf16x8 b, f32x4 c){
  return __builtin_amdgcn_mfma_f32_16x16x32_bf16(a, b, c, 0, 0, 0);
}

// ---------------- setup: transpose+cast all weights to bf16 [h][k] ---------
__global__ __launch_bounds__(256) void k_setup(const float* __restrict__ w_f1,
                                               const float* __restrict__ w_f2,
                                               const float* __restrict__ w_in2f,
                                               const float* __restrict__ w_f2out,
                                               const float* __restrict__ w_out,
                                               const float* __restrict__ w_aw1,
                                               u16* __restrict__ w1t,
                                               u16* __restrict__ w2t,
                                               u16* __restrict__ wi2t,
                                               u16* __restrict__ w2outT,
                                               u16* __restrict__ woutT,
                                               u16* __restrict__ waw1T){
  int idx = blockIdx.x*256 + threadIdx.x;      // < 40960 + 5*16384 = 122880
  if (idx < 128*GP){
    int h = idx / GP, g = idx % GP;
    w1t[idx] = (g < G_) ? f2b(w_f1[g*F_ + h]) : (u16)0;
  } else {
    int j = idx - 128*GP;
    int which = j >> 14;
    int rr = j & 16383;
    int h = rr >> 7, k = rr & 127;
    const float* src; u16* dst;
    switch (which){
      case 0:  src = w_f2;    dst = w2t;    break;
      case 1:  src = w_in2f;  dst = wi2t;   break;
      case 2:  src = w_f2out; dst = w2outT; break;
      case 3:  src = w_out;   dst = woutT;  break;
      default: src = w_aw1;   dst = waw1T;  break;
    }
    dst[h*128 + k] = f2b(src[k*128 + h]);
  }
}

// ---- prep: gentab (blk 0-255) | lin (256-383) | pairidx NN (384-447) ----
__global__ __launch_bounds__(256) void k_prep(const u16* __restrict__ w1t,
                                              const u16* __restrict__ w2t,
                                              const float* __restrict__ b_f1,
                                              const float* __restrict__ b_f2,
                                              u16* __restrict__ tab,
                                              const int* __restrict__ z,
                                              const float* __restrict__ emb,
                                              const u16* __restrict__ wi2t,
                                              u16* __restrict__ fb,
                                              const float* __restrict__ r,
                                              u16* __restrict__ dIdx){
  __shared__ __attribute__((aligned(16))) u16 w1s[16][136];
  __shared__ float rshp[128][3];
  int blk = blockIdx.x;
  int tid = threadIdx.x, lane = tid & 63, wave = tid >> 6;
  int m = lane & 15, q = lane >> 4;

  if (blk < 256){
    // ---- table tile: h(d) for d=(t0+row)/128, MFMA over K1=320, K2=128 ----
    int t0 = blk * 16;
    int C0 = wave*32;
    const float K2 = 14.4269504089f;           // gamma * log2(e)
    const float DC = 30.0f/299.0f;
    float d = (float)(t0 + m) * (1.0f/TAB_SCALE);
    f32x4 acc[2];
    acc[0] = (f32x4){0.f,0.f,0.f,0.f}; acc[1] = (f32x4){0.f,0.f,0.f,0.f};
    #pragma unroll
    for (int ks = 0; ks < 10; ++ks){
      int kb = ks*32 + q*8;
      u32x4 au;
      #pragma unroll
      for (int t2 = 0; t2 < 4; ++t2){
        int k0 = kb + t2*2;
        float u0 = d - DC*(float)k0;
        float u1 = d - DC*(float)(k0 + 1);
        float e0 = __builtin_amdgcn_exp2f(-K2*u0*u0);
        float e1 = __builtin_amdgcn_exp2f(-K2*u1*u1);
        au[t2] = pack2bf(e0, e1);
      }
      bf16x8 af = __builtin_bit_cast(bf16x8, au);
      #pragma unroll
      for (int ni = 0; ni < 2; ++ni){
        bf16x8 bfv = *reinterpret_cast<const bf16x8*>(w1t + (size_t)(C0 + ni*16 + m)*GP + kb);
        acc[ni] = mfma16(af, bfv, acc[ni]);
      }
    }
    #pragma unroll
    for (int ni = 0; ni < 2; ++ni)
      #pragma unroll
      for (int rr = 0; rr < 4; ++rr){
        int col = C0 + ni*16 + m;
        w1s[q*4 + rr][col & 127] = f2b(sspf(acc[ni][rr] + b_f1[col]));
      }
    __syncthreads();
    f32x4 acc2[2];
    acc2[0] = (f32x4){0.f,0.f,0.f,0.f}; acc2[1] = (f32x4){0.f,0.f,0.f,0.f};
    #pragma unroll
    for (int ks = 0; ks < 4; ++ks){
      int kb = ks*32 + q*8;
      bf16x8 af = *reinterpret_cast<const bf16x8*>(&w1s[m][kb]);
      #pragma unroll
      for (int ni = 0; ni < 2; ++ni){
        bf16x8 bfv = *reinterpret_cast<const bf16x8*>(w2t + (size_t)(C0 + ni*16 + m)*128 + kb);
        acc2[ni] = mfma16(af, bfv, acc2[ni]);
      }
    }
    #pragma unroll
    for (int ni = 0; ni < 2; ++ni)
      #pragma unroll
      for (int rr = 0; rr < 4; ++rr){
        int col = C0 + ni*16 + m;
        tab[(size_t)(t0 + q*4 + rr)*F_ + col] = f2b(acc2[ni][rr] + b_f2[col]);
      }
  } else if (blk < 384){
    // ---- f = emb[z] @ w_in2f (first iteration's cfconv input) ----
    int bi = blk - 256;
    int b = bi >> 2, qd = bi & 3;
    int R0 = qd*32 + (wave >> 1)*16;
    int C0 = (wave & 1)*64;
    int row = R0 + m;
    const float* erow = emb + (size_t)z[b*N_ + row]*F_;
    f32x4 acc[4];
    #pragma unroll
    for (int ni = 0; ni < 4; ++ni) acc[ni] = (f32x4){0.f,0.f,0.f,0.f};
    #pragma unroll
    for (int ks = 0; ks < 4; ++ks){
      int k0 = ks*32 + q*8;
      float4 e0 = *reinterpret_cast<const float4*>(erow + k0);
      float4 e1 = *reinterpret_cast<const float4*>(erow + k0 + 4);
      u32x4 au;
      au[0] = pack2bf(e0.x, e0.y); au[1] = pack2bf(e0.z, e0.w);
      au[2] = pack2bf(e1.x, e1.y); au[3] = pack2bf(e1.z, e1.w);
      bf16x8 af = __builtin_bit_cast(bf16x8, au);
      #pragma unroll
      for (int ni = 0; ni < 4; ++ni){
        bf16x8 bfv = *reinterpret_cast<const bf16x8*>(wi2t + (size_t)(C0 + ni*16 + m)*F_ + k0);
        acc[ni] = mfma16(af, bfv, acc[ni]);
      }
    }
    u16* fbb = fb + (size_t)b*N_*F_;
    #pragma unroll
    for (int ni = 0; ni < 4; ++ni)
      #pragma unroll
      for (int rr = 0; rr < 4; ++rr)
        fbb[(size_t)(R0 + q*4 + rr)*F_ + C0 + ni*16 + m] = f2b(acc[ni][rr]);
  } else {
    // ---- pair index (NN): ix = round(|r_i - r_j| * 128), clamp 4095 ----
    int pb = blk - 384;                  // 64 blocks: (b, i-half)
    int b = pb >> 1, i0p = (pb & 1)*64;
    if (tid < 128){
      const float* rp = r + (size_t)(b*N_ + tid)*3;
      rshp[tid][0] = rp[0]; rshp[tid][1] = rp[1]; rshp[tid][2] = rp[2];
    }
    __syncthreads();
    #pragma unroll
    for (int t = 0; t < 32; ++t){
      int p = t*256 + tid;               // (il<64, j<128)
      int il = p >> 7, j = p & 127;
      int i = i0p + il;
      float dx = rshp[i][0] - rshp[j][0];
      float dy = rshp[i][1] - rshp[j][1];
      float dz = rshp[i][2] - rshp[j][2];
      float d = sqrtf(fmaf(dx,dx, fmaf(dy,dy, fmaf(dz,dz, 1e-12f))));
      int ix = (int)(d * TAB_SCALE + 0.5f);
      if (ix > TAB_N - 1) ix = TAB_N - 1;
      dIdx[((size_t)(b*N_ + i))*N_ + j] = (u16)ix;
    }
  }
}

// ---------------- cfconv (NN): y[i,h] = sum_j tab[ix_ij][h] * f[j,h] -------
// grid 2048 = (b, 64 i-tiles of 2). 8 blocks/CU. Thread = (jq8, il2, chg16)
// -- the measured-best map: y[8] accumulators, LDS-staged indices, NO spill.
// NOTE (R9/R11 lesson): at launch_bounds(256,8) the VGPR budget is 64/lane;
// any per-thread index/accumulator array beyond y[8] spills to scratch (2x).
__global__ __launch_bounds__(256, 8) void k_conv(const u16* __restrict__ fb,
                                                 const u16* __restrict__ tab,
                                                 const u16* __restrict__ dIdx,
                                                 u16* __restrict__ yb){
  __shared__ u16 dIdxS[2][128];
  __shared__ __attribute__((aligned(16))) float psh[8][2][128];
  int bid = blockIdx.x;
  int b = bid >> 6, i0 = (bid & 63)*2;
  int tid = threadIdx.x;
  { // stage 256 pair indices (one per thread)
    int il = tid >> 7, j = tid & 127;
    dIdxS[il][j] = dIdx[((size_t)(b*N_ + i0 + il))*N_ + j];
  }
  __syncthreads();

  int chg = tid & 15, il = (tid >> 4) & 1, jq = tid >> 5;
  int h0 = chg*8;
  const u16* tb0 = tab + h0;
  const u16* fbp = fb + (size_t)b*N_*F_ + h0;
  float yv[8] = {0,0,0,0,0,0,0,0};
  #pragma unroll 8
  for (int jj = 0; jj < 16; ++jj){
    int j = jq*16 + jj;
    u32 ix = dIdxS[il][j];
    bf16x8 ta = *reinterpret_cast<const bf16x8*>(tb0 + ((size_t)ix << 7));
    bf16x8 fv = *reinterpret_cast<const bf16x8*>(fbp + (size_t)j*F_);
    #pragma unroll
    for (int t = 0; t < 8; ++t)
      yv[t] = fmaf((float)ta[t], (float)fv[t], yv[t]);
  }
  {
    float* pp = &psh[jq][il][h0];
    *reinterpret_cast<float4*>(pp)     = (float4){yv[0], yv[1], yv[2], yv[3]};
    *reinterpret_cast<float4*>(pp + 4) = (float4){yv[4], yv[5], yv[6], yv[7]};
  }
  __syncthreads();
  int ilo = tid >> 7, cho = tid & 127;
  float s = 0.f;
  #pragma unroll
  for (int t = 0; t < 8; ++t) s += psh[t][ilo][cho];
  yb[((size_t)(b*N_ + i0 + ilo))*F_ + cho] = f2b(s);
}

// ---------------- MLP chain via MFMA (+readout on last) ----------------
// grid 256 (b, 16-row tile) x 512 threads: 8 waves, each owns a 16-col slice.
// (measured-best form: single MFMA chain per GEMM; ILP-2 split was neutral)
__global__ __launch_bounds__(512) void k_mlp(const u16* __restrict__ yb,
                                             float* __restrict__ x,
                                             const int* __restrict__ z,
                                             const float* __restrict__ emb,
                                             const u16* __restrict__ w2outT,
                                             const float* __restrict__ b_f2out,
                                             const u16* __restrict__ woutT,
                                             const float* __restrict__ b_out,
                                             const u16* __restrict__ wi2t,
                                             const u16* __restrict__ waw1T,
                                             const float* __restrict__ b_aw1,
                                             const float* __restrict__ w_aw2,
                                             const float* __restrict__ b_aw2,
                                             u16* __restrict__ fb,
                                             float* __restrict__ outp,
                                             int first, int mode){
  __shared__ __attribute__((aligned(16))) u16 ab[16][136];
  __shared__ float cs[16][132];
  __shared__ float psum[16][8];
  __shared__ int zsh[16];
  int tid = threadIdx.x, lane = tid & 63, wave = tid >> 6;
  int m = lane & 15, q = lane >> 4;
  int bid = blockIdx.x;
  int b = bid >> 3, R0 = (bid & 7)*16;
  int C0 = wave*16;                      // 8 waves x 16 cols
  int col = C0 + m;

  if (first && tid < 16) zsh[tid] = z[b*N_ + R0 + tid];
  { // stage y (already bf16): 512 thr x 4 ch
    int row = tid >> 5, c4 = (tid & 31)*4;
    *reinterpret_cast<u16x4*>(&ab[row][c4]) =
      *reinterpret_cast<const u16x4*>(yb + ((size_t)(b*N_ + R0 + row))*F_ + c4);
  }
  __syncthreads();

  // GEMM1: y @ w_f2out
  f32x4 acc = (f32x4){0.f,0.f,0.f,0.f};
  #pragma unroll
  for (int ks = 0; ks < 4; ++ks){
    int kb = ks*32 + q*8;
    bf16x8 af = *reinterpret_cast<const bf16x8*>(&ab[m][kb]);
    bf16x8 bfv = *reinterpret_cast<const bf16x8*>(w2outT + (size_t)col*F_ + kb);
    acc = mfma16(af, bfv, acc);
  }
  __syncthreads();
  #pragma unroll
  for (int rr = 0; rr < 4; ++rr)
    ab[q*4 + rr][col] = f2b(sspf(acc[rr] + b_f2out[col]));
  __syncthreads();

  // GEMM2: y2 @ w_out
  f32x4 acc2 = (f32x4){0.f,0.f,0.f,0.f};
  #pragma unroll
  for (int ks = 0; ks < 4; ++ks){
    int kb = ks*32 + q*8;
    bf16x8 af = *reinterpret_cast<const bf16x8*>(&ab[m][kb]);
    bf16x8 bfv = *reinterpret_cast<const bf16x8*>(woutT + (size_t)col*F_ + kb);
    acc2 = mfma16(af, bfv, acc2);
  }
  __syncthreads();
  // epilogue: x_new = x_old + v + b_out (in-place x: own rows only)
  #pragma unroll
  for (int rr = 0; rr < 4; ++rr){
    int row = q*4 + rr;
    size_t xo = (size_t)(b*N_ + R0 + row)*F_ + col;
    float xi = first ? emb[(size_t)zsh[row]*F_ + col] : x[xo];
    float nv = xi + acc2[rr] + b_out[col];
    if (mode == 0) x[xo] = nv;
    ab[row][col] = f2b(nv);
  }
  __syncthreads();

  // GEMM3: x_new @ (wi2t | waw1T)
  const u16* w3 = (mode == 0) ? wi2t : waw1T;
  f32x4 acc3 = (f32x4){0.f,0.f,0.f,0.f};
  #pragma unroll
  for (int ks = 0; ks < 4; ++ks){
    int kb = ks*32 + q*8;
    bf16x8 af = *reinterpret_cast<const bf16x8*>(&ab[m][kb]);
    bf16x8 bfv = *reinterpret_cast<const bf16x8*>(w3 + (size_t)col*F_ + kb);
    acc3 = mfma16(af, bfv, acc3);
  }
  if (mode == 0){
    #pragma unroll
    for (int rr = 0; rr < 4; ++rr)
      fb[(size_t)(b*N_ + R0 + q*4 + rr)*F_ + col] = f2b(acc3[rr]);
  } else {
    #pragma unroll
    for (int rr = 0; rr < 4; ++rr)
      cs[q*4 + rr][col] = sspf(acc3[rr] + b_aw1[col]) * w_aw2[col];
    __syncthreads();
    if (tid < 128){
      int row = tid >> 3, seg = tid & 7;
      float s = 0.f;
      #pragma unroll
      for (int t = 0; t < 16; ++t) s += cs[row][seg*16 + t];
      psum[row][seg] = s;
    }
    __syncthreads();
    if (tid < 16){
      float s = 0.f;
      #pragma unroll
      for (int t = 0; t < 8; ++t) s += psum[tid][t];
      outp[b*N_ + R0 + tid] = s + b_aw2[0];
    }
  }
}

extern "C" void kernel_launch(void* const* d_in, const int* in_sizes, int n_in,
                              void* d_out, int out_size, void* d_ws, size_t ws_size,
                              hipStream_t stream){
  const int*   z       = (const int*)d_in[0];
  const float* r       = (const float*)d_in[1];
  const float* emb     = (const float*)d_in[2];
  const float* w_in2f  = (const float*)d_in[3];
  const float* w_f1    = (const float*)d_in[4];
  const float* b_f1    = (const float*)d_in[5];
  const float* w_f2    = (const float*)d_in[6];
  const float* b_f2    = (const float*)d_in[7];
  const float* w_f2out = (const float*)d_in[8];
  const float* b_f2out = (const float*)d_in[9];
  const float* w_out   = (const float*)d_in[10];
  const float* b_out   = (const float*)d_in[11];
  const float* w_aw1   = (const float*)d_in[12];
  const float* b_aw1   = (const float*)d_in[13];
  const float* w_aw2   = (const float*)d_in[14];
  const float* b_aw2   = (const float*)d_in[15];

  // workspace layout (~6.3 MB)
  char* ws = (char*)d_ws;
  float* x     = (float*)(ws);                       // 2,097,152
  u16*   yb    = (u16*)(ws + 2097152);               // 1,048,576
  u16*   fbuf  = (u16*)(ws + 3145728);               // 1,048,576
  u16*   tab   = (u16*)(ws + 4194304);               // 1,048,576 (4096 x 128 bf16)
  u16*   dIdx  = (u16*)(ws + 5242880);               // 1,048,576
  u16*   w1t   = (u16*)(ws + 6291456);               //    81,920
  u16*   w2t   = (u16*)(ws + 6373376);               //    32,768
  u16*   wi2t  = (u16*)(ws + 6406144);               //    32,768
  u16*   w2oT  = (u16*)(ws + 6438912);               //    32,768
  u16*   woT   = (u16*)(ws + 6471680);               //    32,768
  u16*   waw1T = (u16*)(ws + 6504448);               //    32,768

  k_setup<<<480, 256, 0, stream>>>(w_f1, w_f2, w_in2f, w_f2out, w_out, w_aw1,
                                   w1t, w2t, wi2t, w2oT, woT, waw1T);
  k_prep<<<448, 256, 0, stream>>>(w1t, w2t, b_f1, b_f2, tab,
                                  z, emb, wi2t, fbuf, r, dIdx);
  // iter 1
  k_conv<<<2048, 256, 0, stream>>>(fbuf, tab, dIdx, yb);
  k_mlp<<<256, 512, 0, stream>>>(yb, x, z, emb, w2oT, b_f2out, woT, b_out,
                                 wi2t, waw1T, b_aw1, w_aw2, b_aw2,
                                 fbuf, (float*)d_out, 1, 0);
  // iter 2
  k_conv<<<2048, 256, 0, stream>>>(fbuf, tab, dIdx, yb);
  k_mlp<<<256, 512, 0, stream>>>(yb, x, z, emb, w2oT, b_f2out, woT, b_out,
                                 wi2t, waw1T, b_aw1, w_aw2, b_aw2,
                                 fbuf, (float*)d_out, 0, 0);
  // iter 3 (readout fused)
  k_conv<<<2048, 256, 0, stream>>>(fbuf, tab, dIdx, yb);
  k_mlp<<<256, 512, 0, stream>>>(yb, x, z, emb, w2oT, b_f2out, woT, b_out,
                                 wi2t, waw1T, b_aw1, w_aw2, b_aw2,
                                 fbuf, (float*)d_out, 0, 1);
}